// Round 6
// baseline (110.092 us; speedup 1.0000x reference)
//
#include <hip/hip_runtime.h>
#include <hip/hip_bf16.h>

#define BB    262144
#define INF   256
#define HIDF  128
#define OUTF  15
#define NCAM  15
#define TM    64
#define MAXTILES (BB/TM + NCAM)   // 4111

typedef __attribute__((ext_vector_type(8))) short          bf16x8;
typedef __attribute__((ext_vector_type(4))) float          floatx4;
typedef __attribute__((ext_vector_type(4))) int            intx4;
typedef __attribute__((ext_vector_type(4))) unsigned int   uintx4;
typedef __attribute__((ext_vector_type(8))) unsigned short ushortx8;

__device__ __forceinline__ unsigned short f2bf1(float a){
  unsigned int u = __builtin_bit_cast(unsigned int, a);
  u += 0x7fffu + ((u >> 16) & 1u);          // round-to-nearest-even
  return (unsigned short)(u >> 16);
}
__device__ __forceinline__ unsigned int f2bf2(float a, float b){
  return (unsigned int)f2bf1(a) | ((unsigned int)f2bf1(b) << 16);
}

// ---------- fused prepack: W1 pack (blocks 0-239), W2 pack (240-254), zero counters (255) ----------
__global__ void k_prep(const float* __restrict__ W1, const float* __restrict__ W2,
                       unsigned short* __restrict__ W1p, unsigned short* __restrict__ W2p,
                       int* __restrict__ counts, int* __restrict__ scatterOfs){
  int bid = blockIdx.x, tid = threadIdx.x;
  if (bid < 240){
    int t = bid * 256 + tid;
    int l  = t & 63;
    int kf = (t >> 6) & 7;
    int nf = (t >> 9) & 7;
    int c  = t >> 12;
    int col = nf*16 + (l & 15);
    int k0  = kf*32 + (l >> 4)*8;
    ushortx8 v;
    #pragma unroll
    for (int j = 0; j < 8; ++j)
      v[j] = f2bf1(W1[((size_t)c*INF + k0 + j)*HIDF + col]);
    *reinterpret_cast<ushortx8*>(W1p + (size_t)t*8) = v;
  } else if (bid < 255){
    int c  = bid - 240;
    int l  = tid & 63;
    int kf = tid >> 6;            // 0..3
    int col = l & 15;
    int k0  = kf*32 + (l >> 4)*8;
    ushortx8 v;
    #pragma unroll
    for (int j = 0; j < 8; ++j){
      float f = (col < OUTF) ? W2[((size_t)c*HIDF + k0 + j)*OUTF + col] : 0.0f;
      v[j] = f2bf1(f);
    }
    *reinterpret_cast<ushortx8*>(W2p + ((size_t)(c*4 + kf)*64 + l)*8) = v;
  } else {
    if (tid < 16) counts[tid] = 0;
    else if (tid < 32) scatterOfs[tid - 16] = 0;
  }
}

// ---------- histogram ----------
__global__ void k_hist(const int* __restrict__ cam, int* __restrict__ counts){
  __shared__ int lc[NCAM];
  int t = threadIdx.x;
  if (t < NCAM) lc[t] = 0;
  __syncthreads();
  intx4 v = *reinterpret_cast<const intx4*>(cam + (size_t)(blockIdx.x*256 + t)*4);
  atomicAdd(&lc[v[0]], 1); atomicAdd(&lc[v[1]], 1);
  atomicAdd(&lc[v[2]], 1); atomicAdd(&lc[v[3]], 1);
  __syncthreads();
  if (t < NCAM && lc[t]) atomicAdd(&counts[t], lc[t]);
}

// ---------- scatter ----------
__global__ void k_scatter(const int* __restrict__ cam, const int* __restrict__ counts,
                          int* __restrict__ scatterOfs, int* __restrict__ idx){
  __shared__ int lc[NCAM];
  __shared__ int loff[NCAM];
  __shared__ int base[NCAM];
  int t = threadIdx.x;
  if (t < NCAM) lc[t] = 0;
  __syncthreads();
  int start = blockIdx.x * 4096;
  int camr[16], lpos[16];
  #pragma unroll
  for (int j = 0; j < 16; ++j){
    int i = start + j*256 + t;
    camr[j] = cam[i];
    lpos[j] = atomicAdd(&lc[camr[j]], 1);
  }
  __syncthreads();
  if (t == 0){
    int s = 0;
    #pragma unroll
    for (int c = 0; c < NCAM; ++c){ loff[c] = s; s += counts[c]; }
  }
  __syncthreads();
  if (t < NCAM) base[t] = loff[t] + atomicAdd(&scatterOfs[t], lc[t]);
  __syncthreads();
  #pragma unroll
  for (int j = 0; j < 16; ++j)
    idx[base[camr[j]] + lpos[j]] = start + j*256 + t;
}

// ---------- main fused MLP: 4 waves x 16 rows, deep register pipeline ----------
__global__ __launch_bounds__(256, 3) void k_mlp(
    const float* __restrict__ x, const int* __restrict__ idx,
    const int* __restrict__ counts,
    const unsigned short* __restrict__ W1p, const unsigned short* __restrict__ W2p,
    const float* __restrict__ b1, const float* __restrict__ b2,
    float* __restrict__ out)
{
  __shared__ int sidx[TM];
  __shared__ unsigned short hbuf[TM][HIDF];   // 16 KB, XOR-swizzled columns

  int bid = blockIdx.x;
  int c = -1, segStart = 0, rowStart = 0, rows = 0;
  {
    int cum = 0, rcum = 0;
    #pragma unroll 1
    for (int cc = 0; cc < NCAM; ++cc){
      int n  = counts[cc];
      int nt = (n + TM - 1) / TM;
      if (c < 0 && bid < cum + nt){
        c = cc;
        rowStart = (bid - cum) * TM;
        segStart = rcum;
        rows = n - rowStart; if (rows > TM) rows = TM;
      }
      cum += nt; rcum += n;
    }
  }
  if (c < 0) return;

  int t = threadIdx.x;
  if (t < TM){
    int r = (t < rows) ? t : (rows - 1);
    sidx[t] = idx[segStart + rowStart + r];
  }
  __syncthreads();

  int wave = t >> 6, lane = t & 63;
  int wr  = wave * 16;                 // each wave owns 16 rows, all 128 cols
  int l15 = lane & 15, lk = lane >> 4;

  const float* ap = x + (size_t)sidx[wr + l15] * INF + lk*8;
  const unsigned short* bbase = W1p + (size_t)c*32768 + lane*8;

  floatx4 acc[8];
  #pragma unroll
  for (int j = 0; j < 8; ++j) acc[j] = (floatx4)0.0f;

  // pipeline registers: A 4-deep, B 2-deep
  floatx4 a[4][2];
  bf16x8  bfr[2][8];

  #pragma unroll
  for (int s = 0; s < 4; ++s){
    a[s][0] = *reinterpret_cast<const floatx4*>(ap + s*32);
    a[s][1] = *reinterpret_cast<const floatx4*>(ap + s*32 + 4);
  }
  #pragma unroll
  for (int nf = 0; nf < 8; ++nf)
    bfr[0][nf] = *reinterpret_cast<const bf16x8*>(bbase + nf*4096);

  #pragma unroll
  for (int kf = 0; kf < 8; ++kf){
    const int cur  = kf & 3;        // compile-time after unroll
    const int bcur = kf & 1;
    // B prefetch (kf+1) — issued first so B(kf)'s wait never drains the
    // newest A slots
    if (kf < 7){
      #pragma unroll
      for (int nf = 0; nf < 8; ++nf)
        bfr[bcur^1][nf] = *reinterpret_cast<const bf16x8*>(bbase + nf*4096 + (kf+1)*512);
    }
    // convert current A slot to bf16 fragment (waits only on A(kf))
    uintx4 u;
    u[0] = f2bf2(a[cur][0][0], a[cur][0][1]); u[1] = f2bf2(a[cur][0][2], a[cur][0][3]);
    u[2] = f2bf2(a[cur][1][0], a[cur][1][1]); u[3] = f2bf2(a[cur][1][2], a[cur][1][3]);
    bf16x8 af = __builtin_bit_cast(bf16x8, u);
    // A prefetch (kf+4) into the slot just consumed
    if (kf < 4){
      a[cur][0] = *reinterpret_cast<const floatx4*>(ap + (kf+4)*32);
      a[cur][1] = *reinterpret_cast<const floatx4*>(ap + (kf+4)*32 + 4);
    }
    #pragma unroll
    for (int nf = 0; nf < 8; ++nf)
      acc[nf] = __builtin_amdgcn_mfma_f32_16x16x32_bf16(af, bfr[bcur][nf], acc[nf], 0, 0, 0);
  }

  // layer-1 epilogue: bias + relu -> swizzled LDS (bf16)
  #pragma unroll
  for (int nf = 0; nf < 8; ++nf){
    int col = nf*16 + l15;
    float bias = b1[c*HIDF + col];
    #pragma unroll
    for (int j = 0; j < 4; ++j){
      int row = wr + lk*4 + j;
      float h = fmaxf(acc[nf][j] + bias, 0.0f);
      int cb = (col*2) ^ ((row & 7) << 4);
      *reinterpret_cast<unsigned short*>(
          reinterpret_cast<char*>(&hbuf[row][0]) + cb) = f2bf1(h);
    }
  }
  __syncthreads();

  // layer 2: [16 rows x 128] x [128 x 16(pad)]
  floatx4 acc2 = (floatx4)0.0f;
  const unsigned short* wb = W2p + (size_t)c*2048 + lane*8;
  int row2 = wr + l15;
  #pragma unroll
  for (int kf = 0; kf < 4; ++kf){
    bf16x8 wv = *reinterpret_cast<const bf16x8*>(wb + kf*512);
    int cb = (kf*64 + lk*16) ^ ((row2 & 7) << 4);
    bf16x8 av = *reinterpret_cast<const bf16x8*>(
        reinterpret_cast<char*>(&hbuf[row2][0]) + cb);
    acc2 = __builtin_amdgcn_mfma_f32_16x16x32_bf16(av, wv, acc2, 0, 0, 0);
  }

  int col = l15;
  if (col < OUTF){
    float bias2 = b2[c*OUTF + col];
    #pragma unroll
    for (int j = 0; j < 4; ++j){
      int r = wr + lk*4 + j;
      if (r < rows)
        out[(size_t)sidx[r]*OUTF + col] = acc2[j] + bias2;
    }
  }
}

extern "C" void kernel_launch(void* const* d_in, const int* in_sizes, int n_in,
                              void* d_out, int out_size, void* d_ws, size_t ws_size,
                              hipStream_t stream) {
  const float* x  = (const float*)d_in[0];
  const int*   cam= (const int*)d_in[1];
  const float* W1 = (const float*)d_in[2];
  const float* b1 = (const float*)d_in[3];
  const float* W2 = (const float*)d_in[4];
  const float* b2 = (const float*)d_in[5];
  float* out = (float*)d_out;

  char* ws = (char*)d_ws;
  int* counts     = (int*)(ws);          // 16 ints
  int* scatterOfs = (int*)(ws + 64);     // 16 ints
  int* idx        = (int*)(ws + 256);    // BB ints (1 MB)
  unsigned short* W1p = (unsigned short*)(ws + 256 + (size_t)BB*4);       // 983040 B
  unsigned short* W2p = W1p + (size_t)NCAM*8*8*64*8;                      // 61440 B

  hipLaunchKernelGGL(k_prep,    dim3(256),     dim3(256), 0, stream, W1, W2, W1p, W2p, counts, scatterOfs);
  hipLaunchKernelGGL(k_hist,    dim3(256),     dim3(256), 0, stream, cam, counts);
  hipLaunchKernelGGL(k_scatter, dim3(BB/4096), dim3(256), 0, stream, cam, counts, scatterOfs, idx);
  hipLaunchKernelGGL(k_mlp,     dim3(MAXTILES),dim3(256), 0, stream,
                     x, idx, counts, W1p, W2p, b1, b2, out);
}

// Round 7
// 103.104 us; speedup vs baseline: 1.0678x; 1.0678x over previous
//
#include <hip/hip_runtime.h>
#include <hip/hip_bf16.h>

#define BB    262144
#define INF   256
#define HIDF  128
#define OUTF  15
#define NCAM  15
#define TM    128
#define MAXTILES (BB/TM + NCAM)   // 2063

typedef __attribute__((ext_vector_type(8))) short          bf16x8;
typedef __attribute__((ext_vector_type(4))) float          floatx4;
typedef __attribute__((ext_vector_type(4))) int            intx4;
typedef __attribute__((ext_vector_type(4))) unsigned int   uintx4;
typedef __attribute__((ext_vector_type(8))) unsigned short ushortx8;

__device__ __forceinline__ unsigned short f2bf1(float a){
  unsigned int u = __builtin_bit_cast(unsigned int, a);
  u += 0x7fffu + ((u >> 16) & 1u);          // round-to-nearest-even
  return (unsigned short)(u >> 16);
}
__device__ __forceinline__ unsigned int f2bf2(float a, float b){
  return (unsigned int)f2bf1(a) | ((unsigned int)f2bf1(b) << 16);
}

// ---------- fused prepack + histogram (counts/scatterOfs pre-zeroed by memset) ----------
// blocks 0-239: W1 pack; 240-254: W2 pack; 255: idle; 256-511: histogram
__global__ void k_prephist(const float* __restrict__ W1, const float* __restrict__ W2,
                           const int* __restrict__ cam,
                           unsigned short* __restrict__ W1p, unsigned short* __restrict__ W2p,
                           int* __restrict__ counts){
  int bid = blockIdx.x, tid = threadIdx.x;
  if (bid < 240){
    int t = bid * 256 + tid;
    int l  = t & 63;
    int kf = (t >> 6) & 7;
    int nf = (t >> 9) & 7;
    int c  = t >> 12;
    int col = nf*16 + (l & 15);
    int k0  = kf*32 + (l >> 4)*8;
    ushortx8 v;
    #pragma unroll
    for (int j = 0; j < 8; ++j)
      v[j] = f2bf1(W1[((size_t)c*INF + k0 + j)*HIDF + col]);
    *reinterpret_cast<ushortx8*>(W1p + (size_t)t*8) = v;
  } else if (bid < 255){
    int c  = bid - 240;
    int l  = tid & 63;
    int kf = tid >> 6;            // 0..3
    int col = l & 15;
    int k0  = kf*32 + (l >> 4)*8;
    ushortx8 v;
    #pragma unroll
    for (int j = 0; j < 8; ++j){
      float f = (col < OUTF) ? W2[((size_t)c*HIDF + k0 + j)*OUTF + col] : 0.0f;
      v[j] = f2bf1(f);
    }
    *reinterpret_cast<ushortx8*>(W2p + ((size_t)(c*4 + kf)*64 + l)*8) = v;
  } else if (bid >= 256){
    __shared__ int lc[NCAM];
    if (tid < NCAM) lc[tid] = 0;
    __syncthreads();
    intx4 v = *reinterpret_cast<const intx4*>(cam + (size_t)((bid-256)*256 + tid)*4);
    atomicAdd(&lc[v[0]], 1); atomicAdd(&lc[v[1]], 1);
    atomicAdd(&lc[v[2]], 1); atomicAdd(&lc[v[3]], 1);
    __syncthreads();
    if (tid < NCAM && lc[tid]) atomicAdd(&counts[tid], lc[tid]);
  }
}

// ---------- scatter ----------
__global__ void k_scatter(const int* __restrict__ cam, const int* __restrict__ counts,
                          int* __restrict__ scatterOfs, int* __restrict__ idx){
  __shared__ int lc[NCAM];
  __shared__ int loff[NCAM];
  __shared__ int base[NCAM];
  int t = threadIdx.x;
  if (t < NCAM) lc[t] = 0;
  __syncthreads();
  int start = blockIdx.x * 4096;
  int camr[16], lpos[16];
  #pragma unroll
  for (int j = 0; j < 16; ++j){
    int i = start + j*256 + t;
    camr[j] = cam[i];
    lpos[j] = atomicAdd(&lc[camr[j]], 1);
  }
  __syncthreads();
  if (t == 0){
    int s = 0;
    #pragma unroll
    for (int c = 0; c < NCAM; ++c){ loff[c] = s; s += counts[c]; }
  }
  __syncthreads();
  if (t < NCAM) base[t] = loff[t] + atomicAdd(&scatterOfs[t], lc[t]);
  __syncthreads();
  #pragma unroll
  for (int j = 0; j < 16; ++j)
    idx[base[camr[j]] + lpos[j]] = start + j*256 + t;
}

// ---------- main fused MLP: W1 in LDS (lgkm queue), A-gathers alone in vmcnt queue ----------
__global__ __launch_bounds__(256, 2) void k_mlp(
    const float* __restrict__ x, const int* __restrict__ idx,
    const int* __restrict__ counts,
    const unsigned short* __restrict__ W1p, const unsigned short* __restrict__ W2p,
    const float* __restrict__ b1, const float* __restrict__ b2,
    float* __restrict__ out)
{
  __shared__ __align__(16) char smem[65536 + 512];   // w1s (64KB); hbuf aliases first 32KB later
  int* sidx = reinterpret_cast<int*>(smem + 65536);

  int bid = blockIdx.x;
  int c = -1, segStart = 0, rowStart = 0, rows = 0;
  {
    int cum = 0, rcum = 0;
    #pragma unroll 1
    for (int cc = 0; cc < NCAM; ++cc){
      int n  = counts[cc];
      int nt = (n + TM - 1) / TM;
      if (c < 0 && bid < cum + nt){
        c = cc;
        rowStart = (bid - cum) * TM;
        segStart = rcum;
        rows = n - rowStart; if (rows > TM) rows = TM;
      }
      cum += nt; rcum += n;
    }
  }
  if (c < 0) return;

  int t = threadIdx.x;
  int wave = t >> 6, lane = t & 63;

  // stage W1p[c] (64KB) into LDS: 64 chunks of 1KB, direct-to-LDS
  {
    const char* gsrc = reinterpret_cast<const char*>(W1p + (size_t)c*32768);
    #pragma unroll
    for (int i = 0; i < 16; ++i){
      int ci = i*4 + wave;
      __builtin_amdgcn_global_load_lds(
        (const __attribute__((address_space(1))) unsigned int*)(gsrc + ci*1024 + lane*16),
        (__attribute__((address_space(3))) unsigned int*)(smem + ci*1024),
        16, 0, 0);
    }
  }
  if (t < TM){
    int r = (t < rows) ? t : (rows - 1);
    sidx[t] = idx[segStart + rowStart + r];
  }
  __syncthreads();   // w1s + sidx ready (drains staging vmcnt)

  int wr  = wave * 32;                 // each wave owns 32 rows, all 128 cols
  int l15 = lane & 15, lk = lane >> 4;

  const float* ap0 = x + (size_t)sidx[wr + l15]      * INF + lk*8;
  const float* ap1 = x + (size_t)sidx[wr + 16 + l15] * INF + lk*8;

  floatx4 acc[2][8];
  #pragma unroll
  for (int i = 0; i < 2; ++i)
    #pragma unroll
    for (int j = 0; j < 8; ++j) acc[i][j] = (floatx4)0.0f;

  // A pipeline: 4-deep (only vmem traffic in the loop)
  floatx4 a[4][4];
  #pragma unroll
  for (int s = 0; s < 4; ++s){
    a[s][0] = *reinterpret_cast<const floatx4*>(ap0 + s*32);
    a[s][1] = *reinterpret_cast<const floatx4*>(ap0 + s*32 + 4);
    a[s][2] = *reinterpret_cast<const floatx4*>(ap1 + s*32);
    a[s][3] = *reinterpret_cast<const floatx4*>(ap1 + s*32 + 4);
  }

  #pragma unroll
  for (int kf = 0; kf < 8; ++kf){
    const int cur = kf & 3;           // compile-time after unroll
    // B fragments from LDS (lgkmcnt — independent of the A vmcnt queue)
    bf16x8 bf[8];
    #pragma unroll
    for (int nf = 0; nf < 8; ++nf)
      bf[nf] = *reinterpret_cast<const bf16x8*>(smem + (nf*8 + kf)*1024 + lane*16);
    // convert current A slot (waits only on its own gathers)
    uintx4 u0, u1;
    u0[0] = f2bf2(a[cur][0][0], a[cur][0][1]); u0[1] = f2bf2(a[cur][0][2], a[cur][0][3]);
    u0[2] = f2bf2(a[cur][1][0], a[cur][1][1]); u0[3] = f2bf2(a[cur][1][2], a[cur][1][3]);
    u1[0] = f2bf2(a[cur][2][0], a[cur][2][1]); u1[1] = f2bf2(a[cur][2][2], a[cur][2][3]);
    u1[2] = f2bf2(a[cur][3][0], a[cur][3][1]); u1[3] = f2bf2(a[cur][3][2], a[cur][3][3]);
    bf16x8 af0 = __builtin_bit_cast(bf16x8, u0);
    bf16x8 af1 = __builtin_bit_cast(bf16x8, u1);
    // A prefetch (kf+4) into the slot just consumed
    if (kf < 4){
      a[cur][0] = *reinterpret_cast<const floatx4*>(ap0 + (kf+4)*32);
      a[cur][1] = *reinterpret_cast<const floatx4*>(ap0 + (kf+4)*32 + 4);
      a[cur][2] = *reinterpret_cast<const floatx4*>(ap1 + (kf+4)*32);
      a[cur][3] = *reinterpret_cast<const floatx4*>(ap1 + (kf+4)*32 + 4);
    }
    #pragma unroll
    for (int nf = 0; nf < 8; ++nf)
      acc[0][nf] = __builtin_amdgcn_mfma_f32_16x16x32_bf16(af0, bf[nf], acc[0][nf], 0, 0, 0);
    #pragma unroll
    for (int nf = 0; nf < 8; ++nf)
      acc[1][nf] = __builtin_amdgcn_mfma_f32_16x16x32_bf16(af1, bf[nf], acc[1][nf], 0, 0, 0);
  }

  __syncthreads();   // all waves done reading w1s — safe to alias hbuf over it

  // layer-1 epilogue: bias + relu -> swizzled LDS (bf16) in first 32KB
  #pragma unroll
  for (int nf = 0; nf < 8; ++nf){
    int col = nf*16 + l15;
    float bias = b1[c*HIDF + col];
    #pragma unroll
    for (int mf = 0; mf < 2; ++mf){
      #pragma unroll
      for (int j = 0; j < 4; ++j){
        int row = wr + mf*16 + lk*4 + j;
        float h = fmaxf(acc[mf][nf][j] + bias, 0.0f);
        int off = row*256 + ((col*2) ^ ((row & 7) << 4));
        *reinterpret_cast<unsigned short*>(smem + off) = f2bf1(h);
      }
    }
  }
  __syncthreads();

  // layer 2: [32 rows x 128] x [128 x 16(pad)]
  floatx4 acc2[2];
  acc2[0] = (floatx4)0.0f; acc2[1] = (floatx4)0.0f;
  const unsigned short* wb = W2p + (size_t)c*2048 + lane*8;
  #pragma unroll
  for (int kf = 0; kf < 4; ++kf){
    bf16x8 wv = *reinterpret_cast<const bf16x8*>(wb + kf*512);
    #pragma unroll
    for (int mf = 0; mf < 2; ++mf){
      int row = wr + mf*16 + l15;
      int off = row*256 + ((kf*64 + lk*16) ^ ((row & 7) << 4));
      bf16x8 av = *reinterpret_cast<const bf16x8*>(smem + off);
      acc2[mf] = __builtin_amdgcn_mfma_f32_16x16x32_bf16(av, wv, acc2[mf], 0, 0, 0);
    }
  }

  int col = l15;
  if (col < OUTF){
    float bias2 = b2[c*OUTF + col];
    #pragma unroll
    for (int mf = 0; mf < 2; ++mf){
      #pragma unroll
      for (int j = 0; j < 4; ++j){
        int r = wr + mf*16 + lk*4 + j;
        if (r < rows)
          out[(size_t)sidx[r]*OUTF + col] = acc2[mf][j] + bias2;
      }
    }
  }
}

extern "C" void kernel_launch(void* const* d_in, const int* in_sizes, int n_in,
                              void* d_out, int out_size, void* d_ws, size_t ws_size,
                              hipStream_t stream) {
  const float* x  = (const float*)d_in[0];
  const int*   cam= (const int*)d_in[1];
  const float* W1 = (const float*)d_in[2];
  const float* b1 = (const float*)d_in[3];
  const float* W2 = (const float*)d_in[4];
  const float* b2 = (const float*)d_in[5];
  float* out = (float*)d_out;

  char* ws = (char*)d_ws;
  int* counts     = (int*)(ws);          // 16 ints
  int* scatterOfs = (int*)(ws + 64);     // 16 ints
  int* idx        = (int*)(ws + 256);    // BB ints (1 MB)
  unsigned short* W1p = (unsigned short*)(ws + 256 + (size_t)BB*4);       // 983040 B
  unsigned short* W2p = W1p + (size_t)NCAM*8*8*64*8;                      // 61440 B

  (void)hipMemsetAsync(counts, 0, 128, stream);   // counts + scatterOfs
  hipLaunchKernelGGL(k_prephist, dim3(512),     dim3(256), 0, stream, W1, W2, cam, W1p, W2p, counts);
  hipLaunchKernelGGL(k_scatter,  dim3(BB/4096), dim3(256), 0, stream, cam, counts, scatterOfs, idx);
  hipLaunchKernelGGL(k_mlp,      dim3(MAXTILES),dim3(256), 0, stream,
                     x, idx, counts, W1p, W2p, b1, b2, out);
}

// Round 8
// 95.523 us; speedup vs baseline: 1.1525x; 1.0794x over previous
//
#include <hip/hip_runtime.h>
#include <hip/hip_bf16.h>

#define BB    262144
#define INF   256
#define HIDF  128
#define OUTF  15
#define NCAM  15
#define TM    128
#define MAXTILES (BB/TM + NCAM)   // 2063

typedef __attribute__((ext_vector_type(8))) short          bf16x8;
typedef __attribute__((ext_vector_type(4))) float          floatx4;
typedef __attribute__((ext_vector_type(4))) int            intx4;
typedef __attribute__((ext_vector_type(4))) unsigned int   uintx4;
typedef __attribute__((ext_vector_type(8))) unsigned short ushortx8;

__device__ __forceinline__ unsigned short f2bf1(float a){
  unsigned int u = __builtin_bit_cast(unsigned int, a);
  u += 0x7fffu + ((u >> 16) & 1u);          // round-to-nearest-even
  return (unsigned short)(u >> 16);
}
__device__ __forceinline__ unsigned int f2bf2(float a, float b){
  return (unsigned int)f2bf1(a) | ((unsigned int)f2bf1(b) << 16);
}

// ---------- fused prepack + histogram (counts/scatterOfs pre-zeroed by memset) ----------
__global__ void k_prephist(const float* __restrict__ W1, const float* __restrict__ W2,
                           const int* __restrict__ cam,
                           unsigned short* __restrict__ W1p, unsigned short* __restrict__ W2p,
                           int* __restrict__ counts){
  int bid = blockIdx.x, tid = threadIdx.x;
  if (bid < 240){
    int t = bid * 256 + tid;
    int l  = t & 63;
    int kf = (t >> 6) & 7;
    int nf = (t >> 9) & 7;
    int c  = t >> 12;
    int col = nf*16 + (l & 15);
    int k0  = kf*32 + (l >> 4)*8;
    ushortx8 v;
    #pragma unroll
    for (int j = 0; j < 8; ++j)
      v[j] = f2bf1(W1[((size_t)c*INF + k0 + j)*HIDF + col]);
    *reinterpret_cast<ushortx8*>(W1p + (size_t)t*8) = v;
  } else if (bid < 255){
    int c  = bid - 240;
    int l  = tid & 63;
    int kf = tid >> 6;            // 0..3
    int col = l & 15;
    int k0  = kf*32 + (l >> 4)*8;
    ushortx8 v;
    #pragma unroll
    for (int j = 0; j < 8; ++j){
      float f = (col < OUTF) ? W2[((size_t)c*HIDF + k0 + j)*OUTF + col] : 0.0f;
      v[j] = f2bf1(f);
    }
    *reinterpret_cast<ushortx8*>(W2p + ((size_t)(c*4 + kf)*64 + l)*8) = v;
  } else if (bid >= 256){
    __shared__ int lc[NCAM];
    if (tid < NCAM) lc[tid] = 0;
    __syncthreads();
    intx4 v = *reinterpret_cast<const intx4*>(cam + (size_t)((bid-256)*256 + tid)*4);
    atomicAdd(&lc[v[0]], 1); atomicAdd(&lc[v[1]], 1);
    atomicAdd(&lc[v[2]], 1); atomicAdd(&lc[v[3]], 1);
    __syncthreads();
    if (tid < NCAM && lc[tid]) atomicAdd(&counts[tid], lc[tid]);
  }
}

// ---------- scatter ----------
__global__ void k_scatter(const int* __restrict__ cam, const int* __restrict__ counts,
                          int* __restrict__ scatterOfs, int* __restrict__ idx){
  __shared__ int lc[NCAM];
  __shared__ int loff[NCAM];
  __shared__ int base[NCAM];
  int t = threadIdx.x;
  if (t < NCAM) lc[t] = 0;
  __syncthreads();
  int start = blockIdx.x * 4096;
  int camr[16], lpos[16];
  #pragma unroll
  for (int j = 0; j < 16; ++j){
    int i = start + j*256 + t;
    camr[j] = cam[i];
    lpos[j] = atomicAdd(&lc[camr[j]], 1);
  }
  __syncthreads();
  if (t == 0){
    int s = 0;
    #pragma unroll
    for (int c = 0; c < NCAM; ++c){ loff[c] = s; s += counts[c]; }
  }
  __syncthreads();
  if (t < NCAM) base[t] = loff[t] + atomicAdd(&scatterOfs[t], lc[t]);
  __syncthreads();
  #pragma unroll
  for (int j = 0; j < 16; ++j)
    idx[base[camr[j]] + lpos[j]] = start + j*256 + t;
}

// ---------- main fused MLP: A-tile staged f32 direct-to-LDS in K-quarters ----------
// LDS: two 32KB quarter buffers (double-buffered); hbuf aliases buf0 after K-loop.
// Swizzle: within-row 16B unit XOR'd by ((row&7)<<4), applied to the GLOBAL source
// address at staging (linear LDS write) and to the LDS read address (m173 pattern).
__global__ __launch_bounds__(256, 2) void k_mlp(
    const float* __restrict__ x, const int* __restrict__ idx,
    const int* __restrict__ counts,
    const unsigned short* __restrict__ W1p, const unsigned short* __restrict__ W2p,
    const float* __restrict__ b1, const float* __restrict__ b2,
    float* __restrict__ out)
{
  __shared__ __align__(16) char smem[65536];

  int bid = blockIdx.x;
  int c = -1, segStart = 0, rowStart = 0, rows = 0;
  {
    int cum = 0, rcum = 0;
    #pragma unroll 1
    for (int cc = 0; cc < NCAM; ++cc){
      int n  = counts[cc];
      int nt = (n + TM - 1) / TM;
      if (c < 0 && bid < cum + nt){
        c = cc;
        rowStart = (bid - cum) * TM;
        segStart = rcum;
        rows = n - rowStart; if (rows > TM) rows = TM;
      }
      cum += nt; rcum += n;
    }
  }
  if (c < 0) return;

  int t = threadIdx.x;
  int wave = t >> 6, lane = t & 63;
  int wr  = wave * 32;                 // each wave owns rows wr..wr+31
  int l15 = lane & 15, lk = lane >> 4;
  const int* idxBase = idx + segStart + rowStart;

  // per-lane staged-row info: wave stages rowgroups i=0..7 (rows wr+4i+(lane>>4))
  const char* srcp[8];
  {
    int rowsel = lane >> 4;           // 0..3
    int w = (lane & 15) * 16;         // within-row-quarter byte
    #pragma unroll
    for (int i = 0; i < 8; ++i){
      int row = wr + i*4 + rowsel;
      int rc = (row < rows) ? row : (rows - 1);
      int g = idxBase[rc];
      int offr = w ^ (((i*4 + rowsel) & 7) << 4);   // pre-swizzled source offset
      srcp[i] = reinterpret_cast<const char*>(x) + (size_t)g*1024 + offr;
    }
  }

  // staging macro: quarter q -> buf[q&1]; 8 x 1KB direct-to-LDS per wave
  #define STAGE(q) { \
    char* dbase = smem + ((q)&1)*32768 + wave*8192; \
    _Pragma("unroll") \
    for (int i = 0; i < 8; ++i){ \
      __builtin_amdgcn_global_load_lds( \
        (const __attribute__((address_space(1))) unsigned int*)(srcp[i] + (q)*256), \
        (__attribute__((address_space(3))) unsigned int*)(dbase + i*1024), \
        16, 0, 0); \
    } \
  }

  const unsigned short* bbase = W1p + (size_t)c*32768 + lane*8;

  floatx4 acc[2][8];
  #pragma unroll
  for (int i = 0; i < 2; ++i)
    #pragma unroll
    for (int j = 0; j < 8; ++j) acc[i][j] = (floatx4)0.0f;

  bf16x8 bfr[2][8];

  STAGE(0);
  #pragma unroll
  for (int nf = 0; nf < 8; ++nf)
    bfr[0][nf] = *reinterpret_cast<const bf16x8*>(bbase + nf*4096);
  __syncthreads();     // buf0 + B(0) ready

  int swz = (l15 & 7) << 4;     // row&7 == l15&7 for rows wr+mf*16+l15

  #pragma unroll
  for (int q = 0; q < 4; ++q){
    if (q < 3) STAGE(q+1);
    #pragma unroll
    for (int kfl = 0; kfl < 2; ++kfl){
      const int kf = q*2 + kfl;
      if (kf < 7){
        #pragma unroll
        for (int nf = 0; nf < 8; ++nf)
          bfr[(kf+1)&1][nf] = *reinterpret_cast<const bf16x8*>(bbase + nf*4096 + (kf+1)*512);
      }
      // A fragments from LDS (swizzled), convert to bf16
      bf16x8 af[2];
      #pragma unroll
      for (int mf = 0; mf < 2; ++mf){
        int row = wr + mf*16 + l15;
        const char* rbase = smem + (q&1)*32768 + row*256;
        int w1 = kfl*128 + lk*32;
        floatx4 f0 = *reinterpret_cast<const floatx4*>(rbase + (w1 ^ swz));
        floatx4 f1 = *reinterpret_cast<const floatx4*>(rbase + ((w1+16) ^ swz));
        uintx4 u;
        u[0] = f2bf2(f0[0], f0[1]); u[1] = f2bf2(f0[2], f0[3]);
        u[2] = f2bf2(f1[0], f1[1]); u[3] = f2bf2(f1[2], f1[3]);
        af[mf] = __builtin_bit_cast(bf16x8, u);
      }
      #pragma unroll
      for (int nf = 0; nf < 8; ++nf)
        acc[0][nf] = __builtin_amdgcn_mfma_f32_16x16x32_bf16(af[0], bfr[kf&1][nf], acc[0][nf], 0, 0, 0);
      #pragma unroll
      for (int nf = 0; nf < 8; ++nf)
        acc[1][nf] = __builtin_amdgcn_mfma_f32_16x16x32_bf16(af[1], bfr[kf&1][nf], acc[1][nf], 0, 0, 0);
    }
    __syncthreads();   // staging of q+1 complete; buf[q&1] free for reuse
  }

  // layer-1 epilogue: bias + relu -> swizzled LDS (bf16), aliases buf0
  #pragma unroll
  for (int nf = 0; nf < 8; ++nf){
    int col = nf*16 + l15;
    float bias = b1[c*HIDF + col];
    #pragma unroll
    for (int mf = 0; mf < 2; ++mf){
      #pragma unroll
      for (int j = 0; j < 4; ++j){
        int row = wr + mf*16 + lk*4 + j;
        float h = fmaxf(acc[mf][nf][j] + bias, 0.0f);
        int off = row*256 + ((col*2) ^ ((row & 7) << 4));
        *reinterpret_cast<unsigned short*>(smem + off) = f2bf1(h);
      }
    }
  }
  __syncthreads();

  // layer 2: [32 rows x 128] x [128 x 16(pad)]
  floatx4 acc2[2];
  acc2[0] = (floatx4)0.0f; acc2[1] = (floatx4)0.0f;
  const unsigned short* wb = W2p + (size_t)c*2048 + lane*8;
  #pragma unroll
  for (int kf = 0; kf < 4; ++kf){
    bf16x8 wv = *reinterpret_cast<const bf16x8*>(wb + kf*512);
    #pragma unroll
    for (int mf = 0; mf < 2; ++mf){
      int row = wr + mf*16 + l15;
      int off = row*256 + ((kf*64 + lk*16) ^ ((row & 7) << 4));
      bf16x8 av = *reinterpret_cast<const bf16x8*>(smem + off);
      acc2[mf] = __builtin_amdgcn_mfma_f32_16x16x32_bf16(av, wv, acc2[mf], 0, 0, 0);
    }
  }

  int col = l15;
  if (col < OUTF){
    float bias2 = b2[c*OUTF + col];
    #pragma unroll
    for (int mf = 0; mf < 2; ++mf){
      #pragma unroll
      for (int j = 0; j < 4; ++j){
        int r = wr + mf*16 + lk*4 + j;
        if (r < rows)
          out[(size_t)idxBase[r]*OUTF + col] = acc2[mf][j] + bias2;
      }
    }
  }
  #undef STAGE
}

extern "C" void kernel_launch(void* const* d_in, const int* in_sizes, int n_in,
                              void* d_out, int out_size, void* d_ws, size_t ws_size,
                              hipStream_t stream) {
  const float* x  = (const float*)d_in[0];
  const int*   cam= (const int*)d_in[1];
  const float* W1 = (const float*)d_in[2];
  const float* b1 = (const float*)d_in[3];
  const float* W2 = (const float*)d_in[4];
  const float* b2 = (const float*)d_in[5];
  float* out = (float*)d_out;

  char* ws = (char*)d_ws;
  int* counts     = (int*)(ws);          // 16 ints
  int* scatterOfs = (int*)(ws + 64);     // 16 ints
  int* idx        = (int*)(ws + 256);    // BB ints (1 MB)
  unsigned short* W1p = (unsigned short*)(ws + 256 + (size_t)BB*4);       // 983040 B
  unsigned short* W2p = W1p + (size_t)NCAM*8*8*64*8;                      // 61440 B

  (void)hipMemsetAsync(counts, 0, 128, stream);   // counts + scatterOfs
  hipLaunchKernelGGL(k_prephist, dim3(512),     dim3(256), 0, stream, W1, W2, cam, W1p, W2p, counts);
  hipLaunchKernelGGL(k_scatter,  dim3(BB/4096), dim3(256), 0, stream, cam, counts, scatterOfs, idx);
  hipLaunchKernelGGL(k_mlp,      dim3(MAXTILES),dim3(256), 0, stream,
                     x, idx, counts, W1p, W2p, b1, b2, out);
}